// Round 2
// baseline (275.847 us; speedup 1.0000x reference)
//
#include <hip/hip_runtime.h>

#define EMBD 32
#define KN 10

__device__ __forceinline__ float bf2f(unsigned short u) {
    union { unsigned int u; float f; } c; c.u = ((unsigned int)u) << 16; return c.f;
}
__device__ __forceinline__ unsigned short f2bf(float f) {
    union { float f; unsigned int u; } c; c.f = f;
    unsigned int u = c.u + 0x7FFFu + ((c.u >> 16) & 1u);   // RNE
    return (unsigned short)(u >> 16);
}

// f32 -> bf16 table conversion (streaming, ~96 MB traffic)
__global__ __launch_bounds__(256)
void cvt_bf16_kernel(const float4* __restrict__ in, ushort4* __restrict__ out, int n4)
{
    int i = blockIdx.x * 256 + threadIdx.x;
    if (i < n4) {
        float4 v = in[i];
        ushort4 o;
        o.x = f2bf(v.x); o.y = f2bf(v.y); o.z = f2bf(v.z); o.w = f2bf(v.w);
        out[i] = o;
    }
}

// ---------------------------------------------------------------------------
// Pure neighbor gather-mean: agg[r][j] = 0.1 * sum_k feat[nb(r,k)][j], bf16 out.
// No feature LDS, no compute phase, no big barriers -> loads issue continuously
// (tests the phase-starvation theory). 2.8 KB LDS, launch_bounds(256,8) ->
// 32 waves/CU. Each half-wave reads one 64 B bf16 row coalesced.
// ---------------------------------------------------------------------------
template<bool REMAP>
__global__ __launch_bounds__(256, 8)
void agg_gather(const unsigned short* __restrict__ feat,   // [n_nodes,32] bf16
                const int*            __restrict__ neigh,  // [N_NODES,10]
                const int*            __restrict__ remap,  // row -> node (REMAP)
                unsigned short*       __restrict__ aggout, // [n_rows,32] bf16
                int n_rows)
{
    __shared__ int s_nb[64][KN];
    __shared__ int s_node[64];
    const int tid  = threadIdx.x;
    const int row0 = blockIdx.x << 6;

    if constexpr (REMAP) {
        if (tid < 64) {
            int r = row0 + tid;
            if (r >= n_rows) r = n_rows - 1;
            s_node[tid] = remap[r];            // coalesced 256 B
        }
        __syncthreads();
    }

    // stage all 640 neighbor ids, fully parallel (layer1: contiguous 2.5 KB)
    #pragma unroll
    for (int e = tid; e < 64 * KN; e += 256) {
        const int rl = e / KN;
        const int k  = e - rl * KN;
        int node;
        if constexpr (REMAP) node = s_node[rl];
        else { int r = row0 + rl; node = (r >= n_rows) ? n_rows - 1 : r; }
        s_nb[rl][k] = neigh[node * KN + k];
    }
    __syncthreads();

    const int hw = tid >> 5;                   // half-wave 0..7 -> 8 rows each
    const int j  = tid & 31;                   // feature dim
    #pragma unroll 2
    for (int i = 0; i < 8; ++i) {
        const int rl = hw * 8 + i;
        const int r  = row0 + rl;
        float agg = 0.f;
        #pragma unroll
        for (int k = 0; k < KN; ++k)
            agg += bf2f(feat[s_nb[rl][k] * EMBD + j]);     // 64 B coalesced
        if (r < n_rows)
            aggout[r * EMBD + j] = f2bf(agg * 0.1f);       // 64 B coalesced
    }
}

// ---------------------------------------------------------------------------
// Streaming GEMM + ReLU: out[r] = relu([selff[node] | agg[r]] @ W^T).
// gemm1: selff = emb_bf, node = r (sequential), OUT bf16 written IN-PLACE over
//        emb_bf (each block reads only its own 64 rows before the barrier,
//        then overwrites exactly those rows -> no cross-block hazard).
// gemm2: selff = h1_bf, node = node_batch[r] (random 64 B gathers), f32 out.
// Compute phase: wave wid -> outputs [8wid,8wid+8), comb streamed from LDS
// (1 ds_read_b32 shared by 8 FMAs), W base wave-uniform -> scalar K$ loads.
// ---------------------------------------------------------------------------
template<bool SELF_REMAP, bool OUT_BF16>
__global__ __launch_bounds__(256, 4)
void gemm_relu(const unsigned short* __restrict__ selff, // [n_nodes,32] bf16
               const unsigned short* __restrict__ agg,   // [n_rows,32] bf16
               const float*          __restrict__ W,     // [32][64] f32
               const int*            __restrict__ remap, // row -> node
               void*                 __restrict__ out,   // [n_rows,32]
               int n_rows)
{
    __shared__ float sh[64][65];               // [feature][row], +1 pad
    __shared__ int   s_node[64];
    const int tid  = threadIdx.x;
    const int row0 = blockIdx.x << 6;

    if constexpr (SELF_REMAP) {
        if (tid < 64) {
            int r = row0 + tid;
            if (r >= n_rows) r = n_rows - 1;
            s_node[tid] = remap[r];
        }
        __syncthreads();
    }

    // stage [self | agg] feature-major
    {
        const int hw = tid >> 5;
        const int j  = tid & 31;
        #pragma unroll 2
        for (int i = 0; i < 8; ++i) {
            const int rl = hw * 8 + i;
            int r = row0 + rl;
            if (r >= n_rows) r = n_rows - 1;
            const int node = SELF_REMAP ? s_node[rl] : r;
            sh[j][rl]      = bf2f(selff[node * EMBD + j]); // 64 B coalesced
            sh[32 + j][rl] = bf2f(agg[r * EMBD + j]);      // 64 B coalesced
        }
    }
    __syncthreads();

    // compute: wave wid -> outputs [8wid, 8wid+8) for all 64 rows
    const int row = tid & 63;
    const int wid = __builtin_amdgcn_readfirstlane(tid >> 6);
    const float* Wb = W + wid * 8 * 64;        // wave-uniform -> s_load from K$

    float acc[8] = {0.f,0.f,0.f,0.f,0.f,0.f,0.f,0.f};
    #pragma unroll 8
    for (int jj = 0; jj < 64; ++jj) {
        const float c = sh[jj][row];           // stride-1 across lanes
        #pragma unroll
        for (int q = 0; q < 8; ++q)
            acc[q] = fmaf(c, Wb[q * 64 + jj], acc[q]);
    }

    const int r = row0 + row;
    if (r < n_rows) {
        if (OUT_BF16) {
            unsigned int pk[4];
            #pragma unroll
            for (int q = 0; q < 4; ++q) {
                float a0 = fmaxf(acc[2*q],     0.f);
                float a1 = fmaxf(acc[2*q + 1], 0.f);
                pk[q] = (unsigned int)f2bf(a0) | ((unsigned int)f2bf(a1) << 16);
            }
            uint4* dst = (uint4*)((unsigned short*)out + (size_t)r * EMBD + wid * 8);
            *dst = make_uint4(pk[0], pk[1], pk[2], pk[3]);
        } else {
            float* dst = (float*)out + (size_t)r * EMBD + wid * 8;
            ((float4*)dst)[0] = make_float4(fmaxf(acc[0],0.f), fmaxf(acc[1],0.f),
                                            fmaxf(acc[2],0.f), fmaxf(acc[3],0.f));
            ((float4*)dst)[1] = make_float4(fmaxf(acc[4],0.f), fmaxf(acc[5],0.f),
                                            fmaxf(acc[6],0.f), fmaxf(acc[7],0.f));
        }
    }
}

extern "C" void kernel_launch(void* const* d_in, const int* in_sizes, int n_in,
                              void* d_out, int out_size, void* d_ws, size_t ws_size,
                              hipStream_t stream)
{
    // dict order: emb [N,32] f32, W1 [32,64] f32, W2 [32,64] f32,
    //             node_batch [B] i32, neigh [N,10] i32
    const float* emb        = (const float*)d_in[0];
    const float* W1         = (const float*)d_in[1];
    const float* W2         = (const float*)d_in[2];
    const int*   node_batch = (const int*)  d_in[3];
    const int*   neigh      = (const int*)  d_in[4];

    const int N = in_sizes[0] / EMBD;   // 500000
    const int B = in_sizes[3];          // 100000

    // ws layout (64 MB total):
    //   emb_bf [N*32] bf16  -> overwritten in-place by h1_bf in gemm1
    //   agg_bf [N*32] bf16  -> reused for agg2 (only first B*32 used then)
    unsigned short* emb_bf = (unsigned short*)d_ws;
    unsigned short* agg_bf = emb_bf + (size_t)N * EMBD;

    const int n4 = (N * EMBD) / 4;
    cvt_bf16_kernel<<<(n4 + 255) / 256, 256, 0, stream>>>(
        (const float4*)emb, (ushort4*)emb_bf, n4);

    // layer 1: gather-mean over emb, then streaming GEMM (h1 in-place)
    agg_gather<false><<<(N + 63) / 64, 256, 0, stream>>>(
        emb_bf, neigh, nullptr, agg_bf, N);
    gemm_relu<false, true><<<(N + 63) / 64, 256, 0, stream>>>(
        emb_bf, agg_bf, W1, nullptr, (void*)emb_bf /*h1 in-place*/, N);

    // layer 2: gather-mean over h1 for batch rows, then GEMM with remapped self
    agg_gather<true><<<(B + 63) / 64, 256, 0, stream>>>(
        emb_bf /*h1*/, neigh, node_batch, agg_bf, B);
    gemm_relu<true, false><<<(B + 63) / 64, 256, 0, stream>>>(
        emb_bf /*h1*/, agg_bf, W2, node_batch, d_out, B);
}